// Round 1
// baseline (279.515 us; speedup 1.0000x reference)
//
#include <hip/hip_runtime.h>

#define NSITES 32768
#define SPB 16                    // sites per block
#define THREADS 192               // 3 waves; 192 = 16 sites x 12 rows
#define DIAG 4.5f
#define VSTRIDE 100               // psi LDS row stride (floats); 400B keeps float4 alignment (400%16==0)
#define MU_STRIDE (NSITES*144)

__device__ __forceinline__ void cdot4(const float4 kr, const float4 ki,
                                      const float4 vr, const float4 vi,
                                      float& sr, float& si) {
    sr = fmaf(kr.x, vr.x, sr); sr = fmaf(-ki.x, vi.x, sr);
    si = fmaf(kr.x, vi.x, si); si = fmaf(ki.x, vr.x, si);
    sr = fmaf(kr.y, vr.y, sr); sr = fmaf(-ki.y, vi.y, sr);
    si = fmaf(kr.y, vi.y, si); si = fmaf(ki.y, vr.y, si);
    sr = fmaf(kr.z, vr.z, sr); sr = fmaf(-ki.z, vi.z, sr);
    si = fmaf(kr.z, vi.z, si); si = fmaf(ki.z, vr.z, si);
    sr = fmaf(kr.w, vr.w, sr); sr = fmaf(-ki.w, vi.w, sr);
    si = fmaf(kr.w, vi.w, si); si = fmaf(ki.w, vr.w, si);
}

// K goes to REGISTERS, not LDS: each thread consumes exactly its own K row
// (48B re + 48B im per direction), and thread->row mapping is contiguous
// (float offset = tid*12). LDS holds only the staged psi neighbors.
// launch_bounds(192,4): 4 waves/EU -> <=128 VGPR -> ~5 blocks/CU (vs 3 before).
__global__ __launch_bounds__(THREADS, 4) void hop_kernel(
    const float* __restrict__ psi_re, const float* __restrict__ psi_im,
    const float* __restrict__ K_fwd_re, const float* __restrict__ K_fwd_im,
    const float* __restrict__ K_bwd_re, const float* __restrict__ K_bwd_im,
    float* __restrict__ out_re, float* __restrict__ out_im)
{
    __shared__ alignas(16) float vre[SPB][VSTRIDE];              // 6400B
    __shared__ alignas(16) float vim[SPB][VSTRIDE];              // 6400B

    const int tid   = threadIdx.x;
    const int site0 = blockIdx.x * SPB;

    // ---- psi staging (unchanged from verified kernel) ----
    // thread stages one (combo cc, component jj) across 8 sites
    const int jj  = tid % 12;
    const int scb = tid / 12;
    const int cc  = scb & 7;
    const int sb  = scb >> 3;
    const int dt = (cc == 0) - (cc == 1);
    const int dz = (cc == 2) - (cc == 3);
    const int dy = (cc == 4) - (cc == 5);

    float tr[8], ti[8];
    int   dst[8];
    #pragma unroll
    for (int k = 0; k < 8; ++k) {
        const int s2 = sb + 2 * k;
        const int sg = site0 + s2;
        const int x = sg & 7, y = (sg >> 3) & 15, z = (sg >> 7) & 15, t = (sg >> 11) & 15;
        const int r = (t + z + y) & 1;                 // OUT_PARITY = 0
        int dx = 0;
        if (cc == 6) dx =  (r == 1);                   // X fwd where mask_f
        if (cc == 7) dx = -(r == 0);                   // X bwd where mask_b
        const int nt = (t + dt) & 15, nz = (z + dz) & 15,
                  ny = (y + dy) & 15, nx = (x + dx) & 7;
        const int n = ((nt * 16 + nz) * 16 + ny) * 8 + nx;
        tr[k]  = psi_re[n * 12 + jj];
        ti[k]  = psi_im[n * 12 + jj];
        dst[k] = s2 * VSTRIDE + cc * 12 + jj;
    }

    // center psi (coalesced: site*12 + jj == site0*12 + tid)
    const int s    = scb;          // compute-phase local site
    const int site = site0 + s;
    const float pr_c = psi_re[site * 12 + jj];
    const float pi_c = psi_im[site * 12 + jj];

    #pragma unroll
    for (int k = 0; k < 8; ++k) {
        ((float*)vre)[dst[k]] = tr[k];
        ((float*)vim)[dst[k]] = ti[k];
    }

    // ---- K register double-buffer ----
    // per-thread K row base (floats): site*144 + row*12 == site0*144 + tid*12
    const int goff = site0 * 144 + tid * 12;

    float4 a0, a1, a2, a3, a4, a5;     // buffer A (even directions)
    float4 b0, b1, b2, b3, b4, b5;     // buffer B (odd directions)

#define LOADC(c, R0, R1, R2, I0, I1, I2) do { \
    const float* _kr = (((c) & 1) ? K_bwd_re : K_fwd_re) + ((c) >> 1) * MU_STRIDE + goff; \
    const float* _ki = (((c) & 1) ? K_bwd_im : K_fwd_im) + ((c) >> 1) * MU_STRIDE + goff; \
    R0 = ((const float4*)_kr)[0]; R1 = ((const float4*)_kr)[1]; R2 = ((const float4*)_kr)[2]; \
    I0 = ((const float4*)_ki)[0]; I1 = ((const float4*)_ki)[1]; I2 = ((const float4*)_ki)[2]; \
} while (0)

#define COMPUTE(c, R0, R1, R2, I0, I1, I2) do { \
    const float4* v4r = (const float4*)&vre[s][(c) * 12]; \
    const float4* v4i = (const float4*)&vim[s][(c) * 12]; \
    float sr = 0.f, si = 0.f; \
    cdot4(R0, I0, v4r[0], v4i[0], sr, si); \
    cdot4(R1, I1, v4r[1], v4i[1], sr, si); \
    cdot4(R2, I2, v4r[2], v4i[2], sr, si); \
    o_re -= 0.5f * sr; \
    o_im -= 0.5f * si; \
} while (0)

    // prefetch slots 0 and 1 before the barrier: their latency drains
    // together with the staging loads (barrier waits on vmcnt anyway)
    LOADC(0, a0, a1, a2, a3, a4, a5);
    LOADC(1, b0, b1, b2, b3, b4, b5);

    __syncthreads();               // staging writes visible; vmcnt drained

    float o_re = DIAG * pr_c;
    float o_im = DIAG * pi_c;

    // steady state: LOADC(c+2) issued right after buffer freed by COMPUTE(c);
    // compiler inserts s_waitcnt vmcnt(6) before each buffer's first use
    COMPUTE(0, a0, a1, a2, a3, a4, a5);  LOADC(2, a0, a1, a2, a3, a4, a5);
    COMPUTE(1, b0, b1, b2, b3, b4, b5);  LOADC(3, b0, b1, b2, b3, b4, b5);
    COMPUTE(2, a0, a1, a2, a3, a4, a5);  LOADC(4, a0, a1, a2, a3, a4, a5);
    COMPUTE(3, b0, b1, b2, b3, b4, b5);  LOADC(5, b0, b1, b2, b3, b4, b5);
    COMPUTE(4, a0, a1, a2, a3, a4, a5);  LOADC(6, a0, a1, a2, a3, a4, a5);
    COMPUTE(5, b0, b1, b2, b3, b4, b5);  LOADC(7, b0, b1, b2, b3, b4, b5);
    COMPUTE(6, a0, a1, a2, a3, a4, a5);
    COMPUTE(7, b0, b1, b2, b3, b4, b5);

#undef LOADC
#undef COMPUTE

    out_re[site * 12 + jj] = o_re;               // block*192 + tid: fully coalesced
    out_im[site * 12 + jj] = o_im;
}

extern "C" void kernel_launch(void* const* d_in, const int* in_sizes, int n_in,
                              void* d_out, int out_size, void* d_ws, size_t ws_size,
                              hipStream_t stream) {
    const float* psi_re   = (const float*)d_in[0];
    const float* psi_im   = (const float*)d_in[1];
    const float* K_fwd_re = (const float*)d_in[2];
    const float* K_fwd_im = (const float*)d_in[3];
    const float* K_bwd_re = (const float*)d_in[4];
    const float* K_bwd_im = (const float*)d_in[5];
    float* out_re = (float*)d_out;
    float* out_im = out_re + (out_size / 2);    // NSITES*12 = 393216

    hop_kernel<<<NSITES / SPB, THREADS, 0, stream>>>(
        psi_re, psi_im, K_fwd_re, K_fwd_im, K_bwd_re, K_bwd_im, out_re, out_im);
}